// Round 3
// baseline (177.310 us; speedup 1.0000x reference)
//
#include <hip/hip_runtime.h>
#include <math.h>

#define IN_FEATURES 1024
#define OUT_FEATURES 512
#define N_PULSE 10
#define NCOL (IN_FEATURES + N_PULSE)   /* 1034 */
#define BATCH 32
#define MIN_W_ARG -0.3678794411714423
#define CH 32                           /* k-chunk: independent loads per wait */
#define NPAD 1056                       /* NCOL rounded up to CH */

// ---------------- Kernel A: transpose weight [O,N] -> wT [N,O] ----------------
__global__ void transpose_w(const float* __restrict__ w, float* __restrict__ wT) {
    int i = blockIdx.x * blockDim.x + threadIdx.x;
    if (i >= NCOL * OUT_FEATURES) return;
    int n = i / OUT_FEATURES;
    int o = i - n * OUT_FEATURES;
    wT[i] = w[o * NCOL + n];           // coalesced write; strided read L2-served
}

// ----------- Kernel B: rank-by-counting stable argsort + z precompute ---------
// rank(i) = #{ j : key[j] < key[i] || (key[j]==key[i] && j<i) }  == stable
// ascending argsort position. LDS-broadcast inner loop, no barriers in hot loop.
__global__ __launch_bounds__(1024) void rank_sort(
        const float* __restrict__ x, const float* __restrict__ pulse,
        int* __restrict__ order_s, float* __restrict__ t_s,
        double* __restrict__ zs, double* __restrict__ zts) {
    __shared__ float key[NCOL];
    const int b = blockIdx.x;
    const int tid = threadIdx.x;

    for (int e = tid; e < NCOL; e += 1024)
        key[e] = (e < IN_FEATURES) ? x[b * IN_FEATURES + e]
                                   : pulse[e - IN_FEATURES];
    __syncthreads();

    for (int e = tid; e < NCOL; e += 1024) {
        float ke = key[e];
        int r = 0;
        #pragma unroll 8
        for (int j = 0; j < NCOL; ++j) {
            float kj = key[j];                       // same addr all lanes -> broadcast
            r += (kj < ke) || (kj == ke && j < e);
        }
        int dst = b * NCOL + r;
        order_s[dst] = e;
        t_s[dst] = ke;
        double zv = exp((double)ke);                 // all inputs < 1000 -> always valid
        zs[dst]  = zv;
        zts[dst] = zv * (double)ke;
    }
}

// ------------------------- Lambert W0 on [-1/e, 0] ---------------------------
__device__ __forceinline__ double lambertw0(double xx) {
    const double e = 2.718281828459045;
    double w = (xx < -0.25) ? (-1.0 + sqrt(fmax(2.0 * (1.0 + e * xx), 0.0)))
                            : xx * (1.0 - xx);
    #pragma unroll 4
    for (int i = 0; i < 12; ++i) {
        double ew = exp(w);
        double f  = w * ew - xx;
        double denom = ew * (w + 1.0) - (w + 2.0) * f / (2.0 * (w + 1.0) + 1e-12);
        w = w - f / (denom + 1e-12);
    }
    return w;
}

// ----------- Kernel C: per-(b,o) causal scan, first valid crossing -----------
// One wave per block (grid 256 = 32 b x 8 o-blocks): all CUs covered.
// Tables staged in LDS; weights gathered in chunks of CH independent loads so
// one memory wait amortizes over CH k-steps. Exp-free window filter
// (V rising on [t_k,t_{k+1}] since t<1): A*t_k-B <= z_k && A*t_{k+1}-B >= z_{k+1};
// exact Lambert-W + reference conditions re-verified at the candidate k only.
__global__ __launch_bounds__(64) void solve_kernel(
        const float* __restrict__ wT,
        const int* __restrict__ order_s,
        const float* __restrict__ t_s,
        const double* __restrict__ zs,
        const double* __restrict__ zts,
        float* __restrict__ out) {
    __shared__ int    ord_l[NPAD];
    __shared__ float  ts_l[NPAD];
    __shared__ double z_l[NPAD];
    __shared__ double zt_l[NPAD];

    const int b = blockIdx.x >> 3;
    const int o = ((blockIdx.x & 7) << 6) | threadIdx.x;

    for (int e = threadIdx.x; e < NPAD; e += 64) {
        if (e < NCOL) {
            ord_l[e] = order_s[b * NCOL + e];
            ts_l[e]  = t_s[b * NCOL + e];
            z_l[e]   = zs[b * NCOL + e];
            zt_l[e]  = zts[b * NCOL + e];
        } else {
            ord_l[e] = 0; ts_l[e] = 1.0e9f; z_l[e] = 0.0; zt_l[e] = 0.0;
        }
    }
    __syncthreads();

    double A = 0.0, Bv = 0.0;
    float result = 1000.0f;
    bool done = false;

    for (int k0 = 0; k0 < NCOL; k0 += CH) {
        float wreg[CH];
        #pragma unroll
        for (int i = 0; i < CH; ++i)
            wreg[i] = wT[ord_l[k0 + i] * OUT_FEATURES + o];   // CH independent gathers

        #pragma unroll
        for (int i = 0; i < CH; ++i) {
            int k = k0 + i;
            if (done || k >= NCOL) continue;
            double w = (double)wreg[i];
            A  = fma(w, z_l[k],  A);
            Bv = fma(w, zt_l[k], Bv);
            if (!(A > 1e-10)) continue;

            bool last = (k == NCOL - 1);
            float tn = last ? 1000.0f : ts_l[k + 1];
            bool maybe = last ||
                ((fma(A, (double)ts_l[k], -Bv) <= z_l[k]) &&
                 (fma(A, (double)tn,      -Bv) >= z_l[k + 1]));
            if (maybe) {
                double boa = Bv / A;
                double arg = -exp(fmin(boa, 80.0)) / A;
                if (arg >= MIN_W_ARG) {
                    double wl = lambertw0(fmin(fmax(arg, MIN_W_ARG), 0.0));
                    double tc = boa - wl;
                    if (tc >= (double)ts_l[k] && tc <= (double)tn) {
                        result = (float)tc;
                        done = true;
                    }
                }
            }
        }
        if (__ballot(!done) == 0ULL) break;
    }
    out[b * OUT_FEATURES + o] = result;
}

// --------------------------------- launcher ----------------------------------
extern "C" void kernel_launch(void* const* d_in, const int* in_sizes, int n_in,
                              void* d_out, int out_size, void* d_ws, size_t ws_size,
                              hipStream_t stream) {
    const float* x      = (const float*)d_in[0];
    const float* weight = (const float*)d_in[1];
    const float* pulse  = (const float*)d_in[2];
    float* out = (float*)d_out;

    char* ws = (char*)d_ws;
    double* zs  = (double*)ws;                          // 32*1034*8
    double* zts = zs + BATCH * NCOL;                    // 32*1034*8
    float*  wT  = (float*)(zts + BATCH * NCOL);         // 1034*512*4
    float*  t_s = wT + NCOL * OUT_FEATURES;             // 32*1034*4
    int* order_s = (int*)(t_s + BATCH * NCOL);          // 32*1034*4

    hipLaunchKernelGGL(transpose_w,
                       dim3((NCOL * OUT_FEATURES + 255) / 256), dim3(256), 0, stream,
                       weight, wT);
    hipLaunchKernelGGL(rank_sort,
                       dim3(BATCH), dim3(1024), 0, stream,
                       x, pulse, order_s, t_s, zs, zts);
    hipLaunchKernelGGL(solve_kernel,
                       dim3(BATCH * OUT_FEATURES / 64), dim3(64), 0, stream,
                       wT, order_s, t_s, zs, zts, out);
}

// Round 4
// 119.582 us; speedup vs baseline: 1.4827x; 1.4827x over previous
//
#include <hip/hip_runtime.h>
#include <math.h>

#define IN_FEATURES 1024
#define OUT_FEATURES 512
#define N_PULSE 10
#define NCOL (IN_FEATURES + N_PULSE)   /* 1034 */
#define BATCH 32
#define MIN_W_ARG -0.3678794411714423
#define CH 32                           /* k-chunk: independent gathers per wait */
#define NPAD 1056                       /* NCOL rounded up to CH */

/* packed per-batch-row table block: [ord i32 NPAD][ts f32 NPAD][z f64 NPAD][zt f64 NPAD] */
#define OFF_TS  (NPAD * 4)              /* 4224  */
#define OFF_Z   (NPAD * 8)              /* 8448  */
#define OFF_ZT  (NPAD * 16)             /* 16896 */
#define TBL_BYTES (NPAD * 24)           /* 25344 */

// ---------------- Kernel A: transpose weight [O,N] -> wT [N,O] ----------------
__global__ void transpose_w(const float* __restrict__ w, float* __restrict__ wT) {
    int i = blockIdx.x * blockDim.x + threadIdx.x;
    if (i >= NCOL * OUT_FEATURES) return;
    int n = i / OUT_FEATURES;
    int o = i - n * OUT_FEATURES;
    wT[i] = w[o * NCOL + n];           // coalesced write; strided read L2-served
}

// ----------- Kernel B: rank-by-counting stable argsort + z precompute ---------
// 8 parts per batch row -> 256 blocks cover all CUs. Stable rank via single
// u64 compare: key64 = (monotone_bits(t) << 11) | index  (index < 2048).
__global__ __launch_bounds__(256) void rank_sort(
        const float* __restrict__ x, const float* __restrict__ pulse,
        char* __restrict__ tbl) {
    __shared__ unsigned long long sk[NCOL];
    __shared__ float keyf[NCOL];
    const int b    = blockIdx.x >> 3;
    const int part = blockIdx.x & 7;
    const int tid  = threadIdx.x;

    for (int e = tid; e < NCOL; e += 256) {
        float t = (e < IN_FEATURES) ? x[b * IN_FEATURES + e]
                                    : pulse[e - IN_FEATURES];
        unsigned u = __float_as_uint(t);
        u = (u & 0x80000000u) ? ~u : (u | 0x80000000u);   // monotone for all floats
        sk[e]   = ((unsigned long long)u << 11) | (unsigned)e;
        keyf[e] = t;
    }
    __syncthreads();

    char* base = tbl + b * TBL_BYTES;
    int*    ordg = (int*)base;
    float*  tsg  = (float*)(base + OFF_TS);
    double* zg   = (double*)(base + OFF_Z);
    double* ztg  = (double*)(base + OFF_ZT);

    const int e = part * 130 + tid;                       // 8*130 >= 1034
    if (tid < 130 && e < NCOL) {
        unsigned long long mk = sk[e];
        int r = 0;
        #pragma unroll 8
        for (int j = 0; j < NCOL; ++j)
            r += (sk[j] < mk);                            // LDS broadcast, 1 cmp
        float t = keyf[e];
        double zv = exp((double)t);
        ordg[r] = e;
        tsg[r]  = t;
        zg[r]   = zv;
        ztg[r]  = zv * (double)t;
    }
    if (part == 0 && tid >= 232 && tid < 232 + (NPAD - NCOL)) {
        int p = NCOL + (tid - 232);                       // pad entries
        ordg[p] = 0; tsg[p] = 1.0e9f; zg[p] = 0.0; ztg[p] = 0.0;
    }
}

// ------------------------- Lambert W0 on [-1/e, 0] ---------------------------
__device__ __forceinline__ double lambertw0(double xx) {
    const double e = 2.718281828459045;
    double w = (xx < -0.25) ? (-1.0 + sqrt(fmax(2.0 * (1.0 + e * xx), 0.0)))
                            : xx * (1.0 - xx);
    #pragma unroll 4
    for (int i = 0; i < 12; ++i) {
        double ew = exp(w);
        double f  = w * ew - xx;
        double denom = ew * (w + 1.0) - (w + 2.0) * f / (2.0 * (w + 1.0) + 1e-12);
        w = w - f / (denom + 1e-12);
    }
    return w;
}

// ----------- Kernel C: per-(b,o) causal scan, first valid crossing -----------
// Window filter: since t<1 and t_peak = 1+B/A >= 1, V rises on [t_k, t_{k+1}];
// entry condition A*t_k-B <= z_k is implied by the previous window's exit test
// failing (adding spike k doesn't change V at t_k), so only the exit test
// A*t_{k+1}-B >= z_{k+1} is filtered; exact reference conditions re-verified
// at candidate k. Weight gathers double-buffered in CH-chunks.
__global__ __launch_bounds__(64) void solve_kernel(
        const float* __restrict__ wT,
        const char* __restrict__ tbl,
        float* __restrict__ out) {
    __shared__ char smem[TBL_BYTES];
    const int b = blockIdx.x >> 3;
    const int o = ((blockIdx.x & 7) << 6) | threadIdx.x;

    {   // stage the packed per-b table block as wide vector copies
        const uint4* g = (const uint4*)(tbl + b * TBL_BYTES);
        uint4* l = (uint4*)smem;
        #pragma unroll 4
        for (int e = threadIdx.x; e < TBL_BYTES / 16; e += 64)
            l[e] = g[e];
    }
    __syncthreads();
    const int*    ord_l = (const int*)smem;
    const float*  ts_l  = (const float*)(smem + OFF_TS);
    const double* z_l   = (const double*)(smem + OFF_Z);
    const double* zt_l  = (const double*)(smem + OFF_ZT);

    double A = 0.0, Bv = 0.0;
    float result = 1000.0f;
    bool done = false;
    float bufA[CH], bufB[CH];

    auto loadChunk = [&](float* buf, int k0) {
        if (k0 < NCOL) {
            #pragma unroll
            for (int i = 0; i < CH; ++i)
                buf[i] = wT[ord_l[k0 + i] * OUT_FEATURES + o];  // CH indep gathers
        }
    };
    auto process = [&](const float* buf, int k0) {
        if (k0 >= NCOL) return;
        #pragma unroll
        for (int i = 0; i < CH; ++i) {
            int k = k0 + i;
            if (done || k >= NCOL) continue;
            double w = (double)buf[i];
            A  = fma(w, z_l[k],  A);
            Bv = fma(w, zt_l[k], Bv);
            if (!(A > 1e-10)) continue;
            bool last = (k == NCOL - 1);
            float tn = last ? 1000.0f : ts_l[k + 1];
            bool maybe = last || (fma(A, (double)tn, -Bv) >= z_l[k + 1]);
            if (maybe) {
                double boa = Bv / A;
                double arg = -exp(fmin(boa, 80.0)) / A;
                if (arg >= MIN_W_ARG) {
                    double wl = lambertw0(fmin(fmax(arg, MIN_W_ARG), 0.0));
                    double tc = boa - wl;
                    if (tc >= (double)ts_l[k] && tc <= (double)tn) {
                        result = (float)tc;
                        done = true;
                    }
                }
            }
        }
    };

    loadChunk(bufA, 0);
    for (int k0 = 0; k0 < NCOL; k0 += 2 * CH) {
        loadChunk(bufB, k0 + CH);
        process(bufA, k0);
        if (__ballot(!done) == 0ULL) break;
        loadChunk(bufA, k0 + 2 * CH);
        process(bufB, k0 + CH);
        if (__ballot(!done) == 0ULL) break;
    }
    out[b * OUT_FEATURES + o] = result;
}

// --------------------------------- launcher ----------------------------------
extern "C" void kernel_launch(void* const* d_in, const int* in_sizes, int n_in,
                              void* d_out, int out_size, void* d_ws, size_t ws_size,
                              hipStream_t stream) {
    const float* x      = (const float*)d_in[0];
    const float* weight = (const float*)d_in[1];
    const float* pulse  = (const float*)d_in[2];
    float* out = (float*)d_out;

    char* ws = (char*)d_ws;
    float* wT = (float*)ws;                               // 1034*512*4 = 2117632 B
    char*  tbl = ws + (size_t)NCOL * OUT_FEATURES * 4;    // 32 * 25344 B

    hipLaunchKernelGGL(transpose_w,
                       dim3((NCOL * OUT_FEATURES + 255) / 256), dim3(256), 0, stream,
                       weight, wT);
    hipLaunchKernelGGL(rank_sort,
                       dim3(BATCH * 8), dim3(256), 0, stream,
                       x, pulse, tbl);
    hipLaunchKernelGGL(solve_kernel,
                       dim3(BATCH * OUT_FEATURES / 64), dim3(64), 0, stream,
                       wT, tbl, out);
}

// Round 5
// 89.946 us; speedup vs baseline: 1.9713x; 1.3295x over previous
//
#include <hip/hip_runtime.h>
#include <math.h>

#define IN_FEATURES 1024
#define OUT_FEATURES 512
#define N_PULSE 10
#define NCOL 1034
#define BATCH 32
#define MIN_W_ARG -0.3678794411714423
#define CH 16                           /* k-chunk */
#define NK 1040                         /* scan range, multiple of CH */
#define NPAD 1056                       /* table entries = NK + CH (pad) */

/* packed per-b table: [ord i32 NPAD][ts f32 NPAD][z f64 NPAD][zt f64 NPAD] */
#define OFF_TS  (NPAD * 4)
#define OFF_Z   (NPAD * 8)
#define OFF_ZT  (NPAD * 16)
#define TBL_BYTES (NPAD * 24)           /* 25344 */

// -------- Kernel A: tiled transpose weight [O,N] -> wT [N,O], coalesced both ways
__global__ __launch_bounds__(256) void transpose_w(const float* __restrict__ w,
                                                   float* __restrict__ wT) {
    __shared__ float tile[64][65];
    const int n0 = (blockIdx.x % 17) * 64;
    const int o0 = (blockIdx.x / 17) * 64;
    const int tx = threadIdx.x & 63, ty = threadIdx.x >> 6;
    #pragma unroll
    for (int r = 0; r < 16; ++r) {
        int ol = r * 4 + ty;
        int n = n0 + tx;
        if (n < NCOL) tile[ol][tx] = w[(o0 + ol) * NCOL + n];   // coalesced read
    }
    __syncthreads();
    #pragma unroll
    for (int r = 0; r < 16; ++r) {
        int nl = r * 4 + ty;
        int n = n0 + nl;
        if (n < NCOL) wT[n * OUT_FEATURES + o0 + tx] = tile[tx][nl]; // coalesced write
    }
}

// -------- Kernel B: rank-by-counting stable argsort + z precompute ------------
// key64 = (monotone_bits(t) << 11) | index  -> stable rank = one u64 compare.
// LDS reads batched 32-at-a-time into registers (one wait per 32 compares).
__global__ __launch_bounds__(128) void rank_sort(
        const float* __restrict__ x, const float* __restrict__ pulse,
        char* __restrict__ tbl) {
    __shared__ unsigned long long sk[NPAD];
    __shared__ float keyf[NCOL];
    const int b = blockIdx.x / 9, part = blockIdx.x % 9;
    const int tid = threadIdx.x;

    for (int e = tid; e < NPAD; e += 128) {
        if (e < NCOL) {
            float t = (e < IN_FEATURES) ? x[b * IN_FEATURES + e]
                                        : pulse[e - IN_FEATURES];
            unsigned u = __float_as_uint(t);
            u = (u & 0x80000000u) ? ~u : (u | 0x80000000u);
            sk[e] = ((unsigned long long)u << 11) | (unsigned)e;
            keyf[e] = t;
        } else {
            sk[e] = 0xFFFFFFFFFFFFFFFFULL;      // pad: never counted
        }
    }
    __syncthreads();

    char* base = tbl + b * TBL_BYTES;
    int*    ordg = (int*)base;
    float*  tsg  = (float*)(base + OFF_TS);
    double* zg   = (double*)(base + OFF_Z);
    double* ztg  = (double*)(base + OFF_ZT);

    const int e = part * 128 + tid;
    if (e < NCOL) {
        unsigned long long mk = sk[e];
        int r = 0;
        for (int j0 = 0; j0 < NPAD; j0 += 32) {
            unsigned long long c[32];
            #pragma unroll
            for (int i = 0; i < 32; ++i) c[i] = sk[j0 + i];   // batched broadcast
            #pragma unroll
            for (int i = 0; i < 32; ++i) r += (c[i] < mk);
        }
        float t = keyf[e];
        double zv = exp((double)t);
        ordg[r] = e; tsg[r] = t; zg[r] = zv; ztg[r] = zv * (double)t;
    }
    if (part == 8 && tid >= 10) {
        int p = NCOL + (tid - 10);
        if (p < NPAD) { ordg[p] = 0; tsg[p] = -1.0f; zg[p] = 0.0; ztg[p] = 0.0; }
        // pad ts = -1 makes the scan's exit test provably false on pad steps
    }
}

// ------------------------- Lambert W0 on [-1/e, 0] ---------------------------
__device__ __forceinline__ double lambertw0(double xx) {
    const double e = 2.718281828459045;
    double w = (xx < -0.25) ? (-1.0 + sqrt(fmax(2.0 * (1.0 + e * xx), 0.0)))
                            : xx * (1.0 - xx);
    #pragma unroll 4
    for (int i = 0; i < 12; ++i) {
        double ew = exp(w);
        double f  = w * ew - xx;
        double denom = ew * (w + 1.0) - (w + 2.0) * f / (2.0 * (w + 1.0) + 1e-12);
        w = w - f / (denom + 1e-12);
    }
    return w;
}

// -------- Kernel C: branchless filter scan + single deferred Lambert ---------
// Scan filter per k (V rising on window, entry implied by previous exit fail):
//   fire = !done && A>1e-10 && A*t_{k+1} - B >= z_{k+1}
// On fire: cndmask-snapshot (A,B,k); Lambert + exact reference checks run ONCE
// after the scan. Exact-fail => serial exact fallback (provably never needed:
// exact-valid(k) => filter-fire(k), so no earlier k can be missed).
__global__ __launch_bounds__(64) void solve_kernel(
        const float* __restrict__ wT,
        const char* __restrict__ tbl,
        float* __restrict__ out) {
    __shared__ char smem[TBL_BYTES];
    const int b = blockIdx.x >> 3;
    const int o = ((blockIdx.x & 7) << 6) | threadIdx.x;

    {
        const uint4* g = (const uint4*)(tbl + b * TBL_BYTES);
        uint4* l = (uint4*)smem;
        #pragma unroll 4
        for (int e = threadIdx.x; e < TBL_BYTES / 16; e += 64) l[e] = g[e];
    }
    __syncthreads();
    const int*    ord_l = (const int*)smem;
    const float*  ts_l  = (const float*)(smem + OFF_TS);
    const double* z_l   = (const double*)(smem + OFF_Z);
    const double* zt_l  = (const double*)(smem + OFF_ZT);

    double A = 0.0, Bv = 0.0, fA = 0.0, fB = 0.0;
    int fk = 0;
    bool done = false;
    float bufA[CH], bufB[CH];

    auto gather = [&](float* buf, int k0) {
        int idx[CH];
        #pragma unroll
        for (int i = 0; i < CH; ++i) idx[i] = ord_l[k0 + i];
        #pragma unroll
        for (int i = 0; i < CH; ++i) buf[i] = wT[idx[i] * OUT_FEATURES + o];
    };
    auto step = [&](const float* buf, int k0) {
        double tz[CH + 1], tzt[CH];
        float  tts[CH + 1];
        #pragma unroll
        for (int i = 0; i <= CH; ++i) tz[i] = z_l[k0 + i];    // batched LDS reads
        #pragma unroll
        for (int i = 0; i < CH; ++i) tzt[i] = zt_l[k0 + i];
        #pragma unroll
        for (int i = 0; i <= CH; ++i) tts[i] = ts_l[k0 + i];
        #pragma unroll
        for (int i = 0; i < CH; ++i) {                         // straight-line f64
            double w = (double)buf[i];
            A  = fma(w, tz[i],  A);
            Bv = fma(w, tzt[i], Bv);
            bool fire = (!done) & (A > 1e-10) &
                        (fma(A, (double)tts[i + 1], -Bv) >= tz[i + 1]);
            if (fire) { fA = A; fB = Bv; fk = k0 + i; done = true; } // -> cndmask
        }
    };

    gather(bufA, 0);
    for (int k0 = 0; k0 < NK; k0 += 2 * CH) {
        gather(bufB, k0 + CH);
        step(bufA, k0);
        if (__ballot(!done) == 0ULL) break;
        if (k0 + 2 * CH < NK) gather(bufA, k0 + 2 * CH);
        step(bufB, k0 + CH);
        if (__ballot(!done) == 0ULL) break;
    }

    // ---- single Lambert + exact reference verification (once per wave) ----
    double AA, BB, tk, tn;
    bool have;
    if (done) {
        AA = fA; BB = fB;
        tk = (double)ts_l[fk];
        tn = (fk == NCOL - 1) ? 1000.0 : (double)ts_l[fk + 1];
        have = true;
    } else {                                  // last-window (k = NCOL-1) case
        AA = A; BB = Bv;
        tk = (double)ts_l[NCOL - 1];
        tn = 1000.0;
        have = (AA > 1e-10);
    }
    float result = 1000.0f;
    bool need_fb = false;
    if (have) {
        double boa = BB / AA;
        double arg = -exp(fmin(boa, 80.0)) / AA;
        if (arg >= MIN_W_ARG) {
            double wl = lambertw0(fmin(fmax(arg, MIN_W_ARG), 0.0));
            double tc = boa - wl;
            if (tc >= tk && tc <= tn) result = (float)tc;
            else need_fb = done;
        } else need_fb = done;
    }

    // ---- exact serial fallback (fp-boundary safety net; never taken) ----
    if (__ballot(need_fb) != 0ULL) {
        double A2 = fA, B2 = fB;
        for (int k = fk + 1; k < NCOL; ++k) {
            if (!need_fb) break;
            double w = (double)wT[ord_l[k] * OUT_FEATURES + o];
            A2 = fma(w, z_l[k], A2);
            B2 = fma(w, zt_l[k], B2);
            if (!(A2 > 1e-10)) continue;
            double tkk = (double)ts_l[k];
            double tnn = (k == NCOL - 1) ? 1000.0 : (double)ts_l[k + 1];
            double boa = B2 / A2;
            double arg = -exp(fmin(boa, 80.0)) / A2;
            if (arg >= MIN_W_ARG) {
                double wl = lambertw0(fmin(fmax(arg, MIN_W_ARG), 0.0));
                double tc = boa - wl;
                if (tc >= tkk && tc <= tnn) { result = (float)tc; need_fb = false; }
            }
        }
    }
    out[b * OUT_FEATURES + o] = result;
}

// --------------------------------- launcher ----------------------------------
extern "C" void kernel_launch(void* const* d_in, const int* in_sizes, int n_in,
                              void* d_out, int out_size, void* d_ws, size_t ws_size,
                              hipStream_t stream) {
    const float* x      = (const float*)d_in[0];
    const float* weight = (const float*)d_in[1];
    const float* pulse  = (const float*)d_in[2];
    float* out = (float*)d_out;

    char* ws = (char*)d_ws;
    float* wT = (float*)ws;                               // 1034*512*4 B
    char*  tbl = ws + (size_t)NCOL * OUT_FEATURES * 4;    // 32 * 25344 B

    hipLaunchKernelGGL(transpose_w, dim3(17 * 8), dim3(256), 0, stream, weight, wT);
    hipLaunchKernelGGL(rank_sort,   dim3(BATCH * 9), dim3(128), 0, stream, x, pulse, tbl);
    hipLaunchKernelGGL(solve_kernel, dim3(BATCH * OUT_FEATURES / 64), dim3(64), 0, stream,
                       wT, tbl, out);
}